// Round 9
// baseline (226.448 us; speedup 1.0000x reference)
//
#include <hip/hip_runtime.h>
#include <hip/hip_bf16.h>
#include <math.h>

// y[b,i] = sum_j x[b,j] * r[(j-i) mod N] + bias[i]
//        = circular conv: y = IFFT(FFT(x) * FFT(c)) + bias, c[k] = r[(-k) mod N]
// Radix-16 FFT route (N=4096 = 16^3): 3 fwd + 3 inv stages, fp32, in-LDS.
//   - two rows packed per FFT (z = x0 + i*x1), exact for real conv
//   - stage F256 reads x straight from global; I256 writes y straight out
//   - fused middle: F1 + pointwise(C) + I1 in registers (one LDS round-trip)
//   - NO twiddle gathers: per-thread base twiddle, powers by chained cmul
//   - PAD(i)=i+(i>>4): exactly 4 dwords/bank/wave at strides 1,16,256 (optimal)

#define NFFT 4096
#define PAD(i) ((i) + ((i) >> 4))

typedef __attribute__((ext_vector_type(4))) float f32x4;
typedef __attribute__((ext_vector_type(4))) unsigned short us4;

__device__ __forceinline__ float2 cadd(float2 a, float2 b) {
  return make_float2(a.x + b.x, a.y + b.y);
}
__device__ __forceinline__ float2 csub(float2 a, float2 b) {
  return make_float2(a.x - b.x, a.y - b.y);
}
__device__ __forceinline__ float2 cmul(float2 a, float2 b) {
  return make_float2(a.x * b.x - a.y * b.y, a.x * b.y + a.y * b.x);
}
__device__ __forceinline__ float2 cmulj(float2 a, float2 b) {  // a * conj(b)
  return make_float2(a.x * b.x + a.y * b.y, a.y * b.x - a.x * b.y);
}
__device__ __forceinline__ float2 mni(float2 a) {  // a * (-i)
  return make_float2(a.y, -a.x);
}
__device__ __forceinline__ float2 mpi(float2 a) {  // a * (+i)
  return make_float2(-a.y, a.x);
}

#define C1 0.9238795325112867f
#define S1 0.3826834323650898f
#define RQ 0.7071067811865476f

// natural-order DFT-16 (w = e^{-2pi i/16}): 4x4 decomposition.
// X[k1+4k2] = fft4_r( G_r[k1] * w^{r k1} ),  G_r = fft4_c(x[r+4c])
__device__ __forceinline__ void fft16(float2 a[16]) {
  float2 G[4][4];
#pragma unroll
  for (int r = 0; r < 4; ++r) {
    float2 t0 = cadd(a[r], a[r + 8]);
    float2 t1 = csub(a[r], a[r + 8]);
    float2 t2 = cadd(a[r + 4], a[r + 12]);
    float2 t3 = csub(a[r + 4], a[r + 12]);
    G[r][0] = cadd(t0, t2);
    G[r][1] = cadd(t1, mni(t3));
    G[r][2] = csub(t0, t2);
    G[r][3] = cadd(t1, mpi(t3));
  }
  const float2 W1 = make_float2(C1, -S1);
  const float2 W2 = make_float2(RQ, -RQ);
  const float2 W3 = make_float2(S1, -C1);
  const float2 W6 = make_float2(-RQ, -RQ);
  const float2 W9 = make_float2(-C1, S1);
  G[1][1] = cmul(G[1][1], W1);
  G[1][2] = cmul(G[1][2], W2);
  G[1][3] = cmul(G[1][3], W3);
  G[2][1] = cmul(G[2][1], W2);
  G[2][2] = mni(G[2][2]);  // w^4 = -i
  G[2][3] = cmul(G[2][3], W6);
  G[3][1] = cmul(G[3][1], W3);
  G[3][2] = cmul(G[3][2], W6);
  G[3][3] = cmul(G[3][3], W9);
#pragma unroll
  for (int k1 = 0; k1 < 4; ++k1) {
    float2 t0 = cadd(G[0][k1], G[2][k1]);
    float2 t1 = csub(G[0][k1], G[2][k1]);
    float2 t2 = cadd(G[1][k1], G[3][k1]);
    float2 t3 = csub(G[1][k1], G[3][k1]);
    a[k1] = cadd(t0, t2);
    a[k1 + 4] = cadd(t1, mni(t3));
    a[k1 + 8] = csub(t0, t2);
    a[k1 + 12] = cadd(t1, mpi(t3));
  }
}

// natural-order inverse DFT-16 (v = e^{+2pi i/16}), unscaled; exact inverse/16
__device__ __forceinline__ void ifft16(float2 a[16]) {
  float2 G[4][4];
#pragma unroll
  for (int r = 0; r < 4; ++r) {
    float2 t0 = cadd(a[r], a[r + 8]);
    float2 t1 = csub(a[r], a[r + 8]);
    float2 t2 = cadd(a[r + 4], a[r + 12]);
    float2 t3 = csub(a[r + 4], a[r + 12]);
    G[r][0] = cadd(t0, t2);
    G[r][1] = cadd(t1, mpi(t3));
    G[r][2] = csub(t0, t2);
    G[r][3] = cadd(t1, mni(t3));
  }
  const float2 W1 = make_float2(C1, -S1);
  const float2 W2 = make_float2(RQ, -RQ);
  const float2 W3 = make_float2(S1, -C1);
  const float2 W6 = make_float2(-RQ, -RQ);
  const float2 W9 = make_float2(-C1, S1);
  G[1][1] = cmulj(G[1][1], W1);
  G[1][2] = cmulj(G[1][2], W2);
  G[1][3] = cmulj(G[1][3], W3);
  G[2][1] = cmulj(G[2][1], W2);
  G[2][2] = mpi(G[2][2]);  // conj(w^4) = +i
  G[2][3] = cmulj(G[2][3], W6);
  G[3][1] = cmulj(G[3][1], W3);
  G[3][2] = cmulj(G[3][2], W6);
  G[3][3] = cmulj(G[3][3], W9);
#pragma unroll
  for (int k1 = 0; k1 < 4; ++k1) {
    float2 t0 = cadd(G[0][k1], G[2][k1]);
    float2 t1 = csub(G[0][k1], G[2][k1]);
    float2 t2 = cadd(G[1][k1], G[3][k1]);
    float2 t3 = csub(G[1][k1], G[3][k1]);
    a[k1] = cadd(t0, t2);
    a[k1 + 4] = cadd(t1, mpi(t3));
    a[k1 + 8] = csub(t0, t2);
    a[k1 + 12] = cadd(t1, mni(t3));
  }
}

// a[q] *= b^q (q=1..15), chained powers
__device__ __forceinline__ void twiddle_pow(float2 a[16], float2 b) {
  float2 p = b;
  a[1] = cmul(a[1], p);
#pragma unroll
  for (int q = 2; q < 16; ++q) {
    p = cmul(p, b);
    a[q] = cmul(a[q], p);
  }
}
// a[q] *= conj(b^q)
__device__ __forceinline__ void twiddle_pow_conj(float2 a[16], float2 b) {
  float2 p = b;
  a[1] = cmulj(a[1], p);
#pragma unroll
  for (int q = 2; q < 16; ++q) {
    p = cmul(p, b);
    a[q] = cmulj(a[q], p);
  }
}

// ---------------- kernel 0: twiddle table tw[j] = e^{-2pi i j/N} ----------------
__global__ __launch_bounds__(256) void build_tw(float2* __restrict__ twg) {
  const int j = blockIdx.x * 256 + threadIdx.x;
  if (j < NFFT) {
    double ang = (-2.0 * 3.14159265358979323846) * (double)j / (double)NFFT;
    twg[j] = make_float2((float)cos(ang), (float)sin(ang));
  }
}

// ---------------- kernel 1: C = fwd-chain(c), stored in fused order ----------------
__global__ __launch_bounds__(256) void build_C(const float* __restrict__ r,
                                               const float2* __restrict__ twg,
                                               float2* __restrict__ Cg) {
  __shared__ float2 d[PAD(NFFT - 1) + 1];
  const int t = threadIdx.x;
  const float2 w1 = twg[t];
  const float2 w2 = twg[(t & 15) * 16];
  float2 a[16];
  // F256 (reads c[k] = r[(N-k)&mask] from global)
#pragma unroll
  for (int q = 0; q < 16; ++q) {
    const int idx = t + 256 * q;
    a[q] = make_float2(r[(NFFT - idx) & (NFFT - 1)], 0.f);
  }
  fft16(a);
  twiddle_pow(a, w1);
#pragma unroll
  for (int q = 0; q < 16; ++q) d[PAD(t + 256 * q)] = a[q];
  __syncthreads();
  // F16
  const int base16 = (t >> 4) * 256 + (t & 15);
#pragma unroll
  for (int q = 0; q < 16; ++q) a[q] = d[PAD(base16 + 16 * q)];
  fft16(a);
  twiddle_pow(a, w2);
#pragma unroll
  for (int q = 0; q < 16; ++q) d[PAD(base16 + 16 * q)] = a[q];
  __syncthreads();
  // F1 (no twiddle) -> store straight to Cg in the fused stage's layout
  const int base1 = t * 16;
#pragma unroll
  for (int q = 0; q < 16; ++q) a[q] = d[PAD(base1 + q)];
  fft16(a);
#pragma unroll
  for (int q = 0; q < 16; ++q) Cg[base1 + q] = a[q];
}

// ---------------- kernel 2: packed 2-row radix-16 FFT convolution ----------------
__global__ __launch_bounds__(256, 4) void fft_conv3(
    const float* __restrict__ x, const float2* __restrict__ Cg,
    const float2* __restrict__ twg, const float* __restrict__ bias,
    float* __restrict__ y) {
  __shared__ float2 d[PAD(NFFT - 1) + 1];
  const int t = threadIdx.x;
  const size_t r0 = 2 * (size_t)blockIdx.x;
  const float* x0 = x + r0 * NFFT;
  const float* x1 = x0 + NFFT;
  float* y0 = y + r0 * NFFT;
  float* y1 = y0 + NFFT;

  const float2 w1 = twg[t];             // base for F256/I256 (n = t)
  const float2 w2 = twg[(t & 15) * 16]; // base for F16/I16 (n = t&15)

  float2 a[16];

  // ---- F256: global -> regs -> fft16 -> twiddle -> LDS ----
#pragma unroll
  for (int q = 0; q < 16; ++q)
    a[q] = make_float2(x0[t + 256 * q], x1[t + 256 * q]);
  fft16(a);
  twiddle_pow(a, w1);
#pragma unroll
  for (int q = 0; q < 16; ++q) d[PAD(t + 256 * q)] = a[q];
  __syncthreads();

  // ---- F16 ----
  const int base16 = (t >> 4) * 256 + (t & 15);
#pragma unroll
  for (int q = 0; q < 16; ++q) a[q] = d[PAD(base16 + 16 * q)];
  fft16(a);
  twiddle_pow(a, w2);
#pragma unroll
  for (int q = 0; q < 16; ++q) d[PAD(base16 + 16 * q)] = a[q];
  __syncthreads();

  // ---- fused F1 + pointwise(C) + I1 (all in registers) ----
  const int base1 = t * 16;
#pragma unroll
  for (int q = 0; q < 16; ++q) a[q] = d[PAD(base1 + q)];
  fft16(a);
  {
    const float4* c4 = (const float4*)(Cg + base1);  // 128 B contiguous/lane
#pragma unroll
    for (int q = 0; q < 8; ++q) {
      const float4 cc = c4[q];
      a[2 * q] = cmul(a[2 * q], make_float2(cc.x, cc.y));
      a[2 * q + 1] = cmul(a[2 * q + 1], make_float2(cc.z, cc.w));
    }
  }
  ifft16(a);
#pragma unroll
  for (int q = 0; q < 16; ++q) d[PAD(base1 + q)] = a[q];
  __syncthreads();

  // ---- I16: un-twiddle then inverse butterfly ----
#pragma unroll
  for (int q = 0; q < 16; ++q) a[q] = d[PAD(base16 + 16 * q)];
  twiddle_pow_conj(a, w2);
  ifft16(a);
#pragma unroll
  for (int q = 0; q < 16; ++q) d[PAD(base16 + 16 * q)] = a[q];
  __syncthreads();

  // ---- I256 + store (Re -> row0, Im -> row1) ----
#pragma unroll
  for (int q = 0; q < 16; ++q) a[q] = d[PAD(t + 256 * q)];
  twiddle_pow_conj(a, w1);
  ifft16(a);
  const float s = 1.0f / (float)NFFT;
#pragma unroll
  for (int q = 0; q < 16; ++q) {
    const int idx = t + 256 * q;
    const float bv = bias[idx];
    y0[idx] = a[q].x * s + bv;
    y1[idx] = a[q].y * s + bv;
  }
}

// ---------------- fallback GEMM (no ws / odd shapes) ----------------

typedef __attribute__((ext_vector_type(8))) short bf16x8;

__device__ __forceinline__ unsigned short f2bf(float f) {
  union { __hip_bfloat16 h; unsigned short u; } v;
  v.h = __float2bfloat16(f);
  return v.u;
}

#define LDP 72

__global__ __launch_bounds__(256) void circ_gemm_fb(
    const float* __restrict__ x, const float* __restrict__ r,
    const float* __restrict__ bias, float* __restrict__ y, int n) {
  __shared__ unsigned short Asf[128][LDP];
  __shared__ unsigned short Bsf[128][LDP];

  const int tid = threadIdx.x;
  const int wid = tid >> 6;
  const int lane = tid & 63;
  const int bm0 = blockIdx.y * 128;
  const int bn0 = blockIdx.x * 128;
  const int m0w = (wid >> 1) * 64;
  const int n0w = (wid & 1) * 64;
  const int lr = lane & 15;
  const int lk = (lane >> 4) * 8;
  const int mask = n - 1;

  f32x4 acc[4][4];
#pragma unroll
  for (int i = 0; i < 4; ++i)
#pragma unroll
    for (int j = 0; j < 4; ++j) acc[i][j] = (f32x4){0.f, 0.f, 0.f, 0.f};

  const int arow = tid >> 4;
  const int acol = (tid & 15) * 4;
  const int bnn = tid >> 1;
  const int bk0 = (tid & 1) * 32;

  for (int k0 = 0; k0 < n; k0 += 64) {
#pragma unroll
    for (int p = 0; p < 8; ++p) {
      const float4 v =
          *(const float4*)&x[(size_t)(bm0 + arow + p * 16) * n + k0 + acol];
      us4 hh;
      hh.x = f2bf(v.x); hh.y = f2bf(v.y); hh.z = f2bf(v.z); hh.w = f2bf(v.w);
      *(us4*)&Asf[arow + p * 16][acol] = hh;
    }
    {
      const int base = k0 + bk0 - bn0 - bnn;
#pragma unroll
      for (int kq = 0; kq < 32; kq += 4) {
        us4 hh;
        hh.x = f2bf(r[(base + kq + 0) & mask]);
        hh.y = f2bf(r[(base + kq + 1) & mask]);
        hh.z = f2bf(r[(base + kq + 2) & mask]);
        hh.w = f2bf(r[(base + kq + 3) & mask]);
        *(us4*)&Bsf[bnn][bk0 + kq] = hh;
      }
    }
    __syncthreads();

#pragma unroll
    for (int kk = 0; kk < 2; ++kk) {
      bf16x8 af[4], bfr[4];
#pragma unroll
      for (int mi = 0; mi < 4; ++mi)
        af[mi] = *(const bf16x8*)&Asf[m0w + mi * 16 + lr][kk * 32 + lk];
#pragma unroll
      for (int ni = 0; ni < 4; ++ni)
        bfr[ni] = *(const bf16x8*)&Bsf[n0w + ni * 16 + lr][kk * 32 + lk];
#pragma unroll
      for (int mi = 0; mi < 4; ++mi)
#pragma unroll
        for (int ni = 0; ni < 4; ++ni)
          acc[mi][ni] = __builtin_amdgcn_mfma_f32_16x16x32_bf16(
              af[mi], bfr[ni], acc[mi][ni], 0, 0, 0);
    }
    __syncthreads();
  }

#pragma unroll
  for (int ni = 0; ni < 4; ++ni) {
    const int col = bn0 + n0w + ni * 16 + lr;
    const float bv = bias[col];
#pragma unroll
    for (int mi = 0; mi < 4; ++mi) {
      const int row0 = bm0 + m0w + mi * 16 + (lane >> 4) * 4;
#pragma unroll
      for (int j = 0; j < 4; ++j)
        y[(size_t)(row0 + j) * n + col] = acc[mi][ni][j] + bv;
    }
  }
}

// ---------------- launch ----------------

extern "C" void kernel_launch(void* const* d_in, const int* in_sizes, int n_in,
                              void* d_out, int out_size, void* d_ws,
                              size_t ws_size, hipStream_t stream) {
  const float* x = (const float*)d_in[0];
  const float* r = (const float*)d_in[1];
  const float* b = (const float*)d_in[2];
  float* y = (float*)d_out;
  const int n = in_sizes[1];          // 4096
  const int batch = in_sizes[0] / n;  // 8192

  if (n == NFFT && (batch & 1) == 0 && ws_size >= 2 * NFFT * sizeof(float2)) {
    float2* twg = (float2*)d_ws;
    float2* Cg = twg + NFFT;
    build_tw<<<NFFT / 256, 256, 0, stream>>>(twg);
    build_C<<<1, 256, 0, stream>>>(r, twg, Cg);
    fft_conv3<<<batch / 2, 256, 0, stream>>>(x, Cg, twg, b, y);
  } else {
    dim3 grid(n / 128, batch / 128);
    circ_gemm_fb<<<grid, 256, 0, stream>>>(x, r, b, y, n);
  }
}